// Round 3
// baseline (435.163 us; speedup 1.0000x reference)
//
#include <hip/hip_runtime.h>

// TargetMLPReadout: out[b] = sum_{i=1..63} relu(relu([t_b|e_bi] @ W1 + b1) @ W2 + b2)
// Factorization: [t|e] @ W1 = t @ W1_top + e @ W1_bot; t-term shared by all 63 rows.
//
// One block per batch. LDS: A-tile (64x128, row 63 zero-padded) 32K +
// H1 tile 32K + W chunk (16x128) 8K + tpart 0.5K = 72.5 KB -> 2 blocks/CU.
// Thread tile 8 rows x 4 cols, k unrolled x4, float4 LDS reads both sides.

#define DIM   128
#define NODES 64
#define NTN   63     // non-target rows per batch
#define BM    64     // padded row count
#define KC    16     // staged k-chunk

__global__ __launch_bounds__(256, 2)
void target_mlp_readout(const float* __restrict__ embs,
                        const float* __restrict__ W1,
                        const float* __restrict__ b1,
                        const float* __restrict__ W2,
                        const float* __restrict__ b2,
                        float* __restrict__ out) {
    __shared__ float sA[BM][DIM];   // layer-1 A operand; reused as reduction scratch
    __shared__ float sH[BM][DIM];   // tpart partials, then layer-1 output
    __shared__ float sW[KC][DIM];   // weight chunk
    __shared__ float sT[DIM];       // tpart (target @ W1_top + b1)

    const int b   = blockIdx.x;
    const int tid = threadIdx.x;
    const int tx  = tid & 31;       // col tile -> cols c0..c0+3
    const int ty  = tid >> 5;       // row tile -> rows r0..r0+7
    const int c0  = tx * 4;
    const int r0  = ty * 8;
    const float* eb = embs + (size_t)b * (NODES * DIM);

    // ---- stage non-target rows (nodes 1..63), zero-pad row 63 ----
    for (int u = tid; u < BM * (DIM / 4); u += 256) {
        const int row = u >> 5;
        const int c4  = (u & 31) << 2;
        float4 v = make_float4(0.f, 0.f, 0.f, 0.f);
        if (row < NTN) v = *(const float4*)(eb + (size_t)(row + 1) * DIM + c4);
        *(float4*)&sA[row][c4] = v;
    }

    // ---- tpart[j] = b1[j] + sum_k target[k] * W1[k][j]  (W1 top half) ----
    {
        const int j = tid & (DIM - 1);
        const int h = tid >> 7;          // two threads split k-range per j
        const int kbeg = h * 64;
        float p = (h == 0) ? b1[j] : 0.f;
        #pragma unroll 8
        for (int k = 0; k < 64; ++k)
            p = fmaf(eb[kbeg + k], W1[(size_t)(kbeg + k) * DIM + j], p);
        ((float*)sH)[tid] = p;
        __syncthreads();
        if (tid < DIM) sT[tid] = ((float*)sH)[tid] + ((float*)sH)[DIM + tid];
        __syncthreads();
    }

    float acc[8][4];

    // ================= layer 1: H1 = relu(tpart + A @ W1_bot) =================
    #pragma unroll
    for (int r = 0; r < 8; ++r) {
        acc[r][0] = sT[c0 + 0]; acc[r][1] = sT[c0 + 1];
        acc[r][2] = sT[c0 + 2]; acc[r][3] = sT[c0 + 3];
    }
    {
        const float* Wsrc = W1 + (size_t)DIM * DIM;   // bottom half
        for (int kc = 0; kc < DIM; kc += KC) {
            __syncthreads();   // protect sW from previous chunk's readers
            for (int u = tid; u < KC * (DIM / 4); u += 256) {
                const int kr = u >> 5;
                const int c4 = (u & 31) << 2;
                *(float4*)&sW[kr][c4] = *(const float4*)(Wsrc + (size_t)(kc + kr) * DIM + c4);
            }
            __syncthreads();
            #pragma unroll
            for (int k = 0; k < KC; k += 4) {
                const float4 w0 = *(const float4*)&sW[k + 0][c0];
                const float4 w1 = *(const float4*)&sW[k + 1][c0];
                const float4 w2 = *(const float4*)&sW[k + 2][c0];
                const float4 w3 = *(const float4*)&sW[k + 3][c0];
                #pragma unroll
                for (int r = 0; r < 8; ++r) {
                    const float4 a = *(const float4*)&sA[r0 + r][kc + k];
                    acc[r][0] = fmaf(a.x, w0.x, fmaf(a.y, w1.x, fmaf(a.z, w2.x, fmaf(a.w, w3.x, acc[r][0]))));
                    acc[r][1] = fmaf(a.x, w0.y, fmaf(a.y, w1.y, fmaf(a.z, w2.y, fmaf(a.w, w3.y, acc[r][1]))));
                    acc[r][2] = fmaf(a.x, w0.z, fmaf(a.y, w1.z, fmaf(a.z, w2.z, fmaf(a.w, w3.z, acc[r][2]))));
                    acc[r][3] = fmaf(a.x, w0.w, fmaf(a.y, w1.w, fmaf(a.z, w2.w, fmaf(a.w, w3.w, acc[r][3]))));
                }
            }
        }
    }
    // relu -> store H1 (no barrier needed: private tiles; next chunk barrier orders reads)
    #pragma unroll
    for (int r = 0; r < 8; ++r) {
        float4 hv;
        hv.x = fmaxf(acc[r][0], 0.f); hv.y = fmaxf(acc[r][1], 0.f);
        hv.z = fmaxf(acc[r][2], 0.f); hv.w = fmaxf(acc[r][3], 0.f);
        *(float4*)&sH[r0 + r][c0] = hv;
    }

    // ================= layer 2: H2 = relu(b2 + H1 @ W2) =================
    {
        const float4 bv = *(const float4*)(b2 + c0);
        #pragma unroll
        for (int r = 0; r < 8; ++r) {
            acc[r][0] = bv.x; acc[r][1] = bv.y; acc[r][2] = bv.z; acc[r][3] = bv.w;
        }
        for (int kc = 0; kc < DIM; kc += KC) {
            __syncthreads();   // also makes H1 stores visible before first reads
            for (int u = tid; u < KC * (DIM / 4); u += 256) {
                const int kr = u >> 5;
                const int c4 = (u & 31) << 2;
                *(float4*)&sW[kr][c4] = *(const float4*)(W2 + (size_t)(kc + kr) * DIM + c4);
            }
            __syncthreads();
            #pragma unroll
            for (int k = 0; k < KC; k += 4) {
                const float4 w0 = *(const float4*)&sW[k + 0][c0];
                const float4 w1 = *(const float4*)&sW[k + 1][c0];
                const float4 w2 = *(const float4*)&sW[k + 2][c0];
                const float4 w3 = *(const float4*)&sW[k + 3][c0];
                #pragma unroll
                for (int r = 0; r < 8; ++r) {
                    const float4 a = *(const float4*)&sH[r0 + r][kc + k];
                    acc[r][0] = fmaf(a.x, w0.x, fmaf(a.y, w1.x, fmaf(a.z, w2.x, fmaf(a.w, w3.x, acc[r][0]))));
                    acc[r][1] = fmaf(a.x, w0.y, fmaf(a.y, w1.y, fmaf(a.z, w2.y, fmaf(a.w, w3.y, acc[r][1]))));
                    acc[r][2] = fmaf(a.x, w0.z, fmaf(a.y, w1.z, fmaf(a.z, w2.z, fmaf(a.w, w3.z, acc[r][2]))));
                    acc[r][3] = fmaf(a.x, w0.w, fmaf(a.y, w1.w, fmaf(a.z, w2.w, fmaf(a.w, w3.w, acc[r][3]))));
                }
            }
        }
    }

    // ---- relu + per-thread column partial sum (exclude padded row 63) ----
    float4 cs = make_float4(0.f, 0.f, 0.f, 0.f);
    #pragma unroll
    for (int r = 0; r < 8; ++r) {
        if (r0 + r < NTN) {
            cs.x += fmaxf(acc[r][0], 0.f);
            cs.y += fmaxf(acc[r][1], 0.f);
            cs.z += fmaxf(acc[r][2], 0.f);
            cs.w += fmaxf(acc[r][3], 0.f);
        }
    }
    __syncthreads();               // everyone past last sW/sH reads
    *(float4*)&sA[ty][c0] = cs;    // reuse sA rows 0..7 as reduction scratch
    __syncthreads();
    if (tid < DIM) {
        float s = 0.f;
        #pragma unroll
        for (int t = 0; t < 8; ++t) s += sA[t][tid];
        out[(size_t)b * DIM + tid] = s;
    }
}

extern "C" void kernel_launch(void* const* d_in, const int* in_sizes, int n_in,
                              void* d_out, int out_size, void* d_ws, size_t ws_size,
                              hipStream_t stream) {
    const float* embs = (const float*)d_in[0];
    // d_in[1] = batch_idx: deterministically row's batch -> unused
    const float* W1   = (const float*)d_in[2];
    const float* b1   = (const float*)d_in[3];
    const float* W2   = (const float*)d_in[4];
    const float* b2   = (const float*)d_in[5];
    float* out        = (float*)d_out;

    const int nb = in_sizes[0] / (NODES * DIM);   // 4096
    target_mlp_readout<<<nb, 256, 0, stream>>>(embs, W1, b1, W2, b2, out);
}

// Round 4
// 273.926 us; speedup vs baseline: 1.5886x; 1.5886x over previous
//
#include <hip/hip_runtime.h>

// TargetMLPReadout via bf16x3 split-precision MFMA (gfx950).
// out[b] = sum_{i=1..63} relu(relu([t_b|e_bi]@W1 + b1) @ W2 + b2)
//   = sum rows of relu(relu(tpart + A@W1bot) @ W2 + b2),  tpart = b1 + t@W1top (fp32 exact)
// Split each fp32 operand x = hi + lo (bf16 RNE);  X@Y ~= Xhi@Yhi + Xhi@Ylo + Xlo@Yhi
// (rel err ~1e-5, i.e. fp32-grade; 3x MFMA cost, still ~10x over the VALU path).
//
// pack_wt: W1bot^T / W2^T -> hi/lo bf16 planes in d_ws (128 KB, L2-hot, read as
// B-fragments straight from global: lane reads WT[n][k0..k0+8] contiguous 16B).
// Main: 1 block/batch, 4 waves, per-wave 64x32 output tile, mfma_f32_16x16x32_bf16.
// A (and later H1) staged in LDS hi/lo bf16 with XOR swizzle byte^=((row&7)<<4)
// -> fragment ds_read_b128 is 2-way (free). LDS 33.5 KB -> 4 blocks/CU (16 waves).

#define DIM   128
#define NODES 64
#define NTN   63

typedef short bf16x8 __attribute__((ext_vector_type(8)));
typedef float f32x4  __attribute__((ext_vector_type(4)));

__device__ __forceinline__ unsigned short f2bf(float f) {   // RNE fp32->bf16 (no NaN inputs)
    unsigned int u = __float_as_uint(f);
    u += 0x7FFFu + ((u >> 16) & 1u);
    return (unsigned short)(u >> 16);
}
__device__ __forceinline__ float bf2f(unsigned short h) {
    return __uint_as_float(((unsigned int)h) << 16);
}

// ws layout (ushort): [layer 0: W1bot][layer 1: W2], each = hi plane [n][k] 128x128
// then lo plane [n][k] 128x128.  Layer stride 32768, plane stride 16384. 128 KB total.
__global__ void pack_wt(const float* __restrict__ W1,
                        const float* __restrict__ W2,
                        unsigned short* __restrict__ wt) {
    const int b     = blockIdx.x;        // 0..255
    const int layer = b >> 7;
    const int n     = b & 127;
    const int k     = threadIdx.x;       // 0..127
    const float* W  = layer ? W2 : (W1 + DIM * DIM);   // layer 0 uses W1 bottom half
    const float w   = W[k * DIM + n];
    const unsigned short hi = f2bf(w);
    const unsigned short lo = f2bf(w - bf2f(hi));
    unsigned short* base = wt + layer * (2 * DIM * DIM);
    base[n * DIM + k]             = hi;
    base[DIM * DIM + n * DIM + k] = lo;
}

// One bf16x3 GEMM over K=128: acc[4][2] += A(64x128, LDS hi/lo swizzled) @ B(128x32 cols of wave)
__device__ __forceinline__ void gemm3(f32x4 acc[4][2],
                                      const unsigned short* sA_hi,
                                      const unsigned short* sA_lo,
                                      const unsigned short* __restrict__ bhi,
                                      const unsigned short* __restrict__ blo,
                                      int w, int l15, int g) {
    #pragma unroll
    for (int kk = 0; kk < 4; ++kk) {
        const int k0 = kk * 32 + g * 8;
        const bf16x8 bh0 = *(const bf16x8*)(bhi + (w * 32 + l15) * DIM + k0);
        const bf16x8 bl0 = *(const bf16x8*)(blo + (w * 32 + l15) * DIM + k0);
        const bf16x8 bh1 = *(const bf16x8*)(bhi + (w * 32 + 16 + l15) * DIM + k0);
        const bf16x8 bl1 = *(const bf16x8*)(blo + (w * 32 + 16 + l15) * DIM + k0);
        #pragma unroll
        for (int mi = 0; mi < 4; ++mi) {
            const int row = mi * 16 + l15;
            const int byt = row * 256 + ((k0 * 2) ^ ((row & 7) << 4));
            const bf16x8 ah = *(const bf16x8*)((const char*)sA_hi + byt);
            const bf16x8 al = *(const bf16x8*)((const char*)sA_lo + byt);
            acc[mi][0] = __builtin_amdgcn_mfma_f32_16x16x32_bf16(ah, bh0, acc[mi][0], 0, 0, 0);
            acc[mi][0] = __builtin_amdgcn_mfma_f32_16x16x32_bf16(ah, bl0, acc[mi][0], 0, 0, 0);
            acc[mi][0] = __builtin_amdgcn_mfma_f32_16x16x32_bf16(al, bh0, acc[mi][0], 0, 0, 0);
            acc[mi][1] = __builtin_amdgcn_mfma_f32_16x16x32_bf16(ah, bh1, acc[mi][1], 0, 0, 0);
            acc[mi][1] = __builtin_amdgcn_mfma_f32_16x16x32_bf16(ah, bl1, acc[mi][1], 0, 0, 0);
            acc[mi][1] = __builtin_amdgcn_mfma_f32_16x16x32_bf16(al, bh1, acc[mi][1], 0, 0, 0);
        }
    }
}

__global__ __launch_bounds__(256, 4)
void mlp_mfma(const float* __restrict__ embs,
              const float* __restrict__ W1,
              const float* __restrict__ b1,
              const float* __restrict__ b2,
              const unsigned short* __restrict__ wt,
              float* __restrict__ out) {
    __shared__ unsigned short sHi[64 * DIM];   // 16 KB, XOR-swizzled; A then H1
    __shared__ unsigned short sLo[64 * DIM];   // 16 KB
    __shared__ float sT[DIM];                  // tpart
    __shared__ float sP[256];                  // tpart partials

    const int b   = blockIdx.x;
    const int tid = threadIdx.x;
    const int w   = tid >> 6;                  // wave id: N-cols [32w, 32w+32)
    const int ln  = tid & 63;
    const int l15 = ln & 15;
    const int g   = ln >> 4;                   // quarter-wave group
    const float* eb = embs + (size_t)b * (NODES * DIM);

    // ---- stage A rows (nodes 1..63) as hi/lo bf16, row 63 zero, swizzled ----
    #pragma unroll
    for (int u = tid; u < 64 * 32; u += 256) {
        const int row = u >> 5;
        const int c0  = (u & 31) * 4;          // element col (step 4)
        float4 v = make_float4(0.f, 0.f, 0.f, 0.f);
        if (row < NTN) v = *(const float4*)(eb + (row + 1) * DIM + c0);
        const float vf[4] = {v.x, v.y, v.z, v.w};
        unsigned int hp[2], lp[2];
        #pragma unroll
        for (int e = 0; e < 2; ++e) {
            const unsigned short h0 = f2bf(vf[2 * e]),     h1 = f2bf(vf[2 * e + 1]);
            const unsigned short q0 = f2bf(vf[2 * e]     - bf2f(h0));
            const unsigned short q1 = f2bf(vf[2 * e + 1] - bf2f(h1));
            hp[e] = (unsigned int)h0 | ((unsigned int)h1 << 16);
            lp[e] = (unsigned int)q0 | ((unsigned int)q1 << 16);
        }
        const int byt = row * 256 + ((c0 * 2) ^ ((row & 7) << 4));  // 8B-aligned, swizzle-safe
        *(uint2*)((char*)sHi + byt) = make_uint2(hp[0], hp[1]);
        *(uint2*)((char*)sLo + byt) = make_uint2(lp[0], lp[1]);
    }

    // ---- tpart[j] = b1[j] + t @ W1top (fp32 exact) ----
    {
        const int j  = tid & 127;
        const int h  = tid >> 7;
        const int kb = h * 64;
        float p = h ? 0.f : b1[j];
        #pragma unroll 4
        for (int k = 0; k < 64; ++k)
            p = fmaf(eb[kb + k], W1[(kb + k) * DIM + j], p);
        sP[tid] = p;
    }
    __syncthreads();
    if (tid < DIM) sT[tid] = sP[tid] + sP[DIM + tid];
    __syncthreads();

    const unsigned short* w1hi = wt;
    const unsigned short* w1lo = wt + DIM * DIM;
    const unsigned short* w2hi = wt + 2 * DIM * DIM;
    const unsigned short* w2lo = wt + 3 * DIM * DIM;

    // ================= layer 1 =================
    f32x4 acc[4][2];
    {
        const float t0 = sT[w * 32 + l15];
        const float t1 = sT[w * 32 + 16 + l15];
        #pragma unroll
        for (int mi = 0; mi < 4; ++mi) {
            acc[mi][0] = (f32x4){t0, t0, t0, t0};
            acc[mi][1] = (f32x4){t1, t1, t1, t1};
        }
    }
    gemm3(acc, sHi, sLo, w1hi, w1lo, w, l15, g);
    __syncthreads();                       // all waves done reading A from sHi/sLo

    // relu -> H1 hi/lo back into sHi/sLo (C layout: col=l15(+16nj), row=16mi+4g+r)
    #pragma unroll
    for (int mi = 0; mi < 4; ++mi)
        #pragma unroll
        for (int nj = 0; nj < 2; ++nj)
            #pragma unroll
            for (int r = 0; r < 4; ++r) {
                const int row = mi * 16 + g * 4 + r;
                const int col = w * 32 + nj * 16 + l15;
                const float v = fmaxf(acc[mi][nj][r], 0.f);
                const unsigned short h = f2bf(v);
                const unsigned short l = f2bf(v - bf2f(h));
                const int byt = row * 256 + ((col * 2) ^ ((row & 7) << 4));
                *(unsigned short*)((char*)sHi + byt) = h;
                *(unsigned short*)((char*)sLo + byt) = l;
            }
    __syncthreads();

    // ================= layer 2 =================
    {
        const float t0 = b2[w * 32 + l15];
        const float t1 = b2[w * 32 + 16 + l15];
        #pragma unroll
        for (int mi = 0; mi < 4; ++mi) {
            acc[mi][0] = (f32x4){t0, t0, t0, t0};
            acc[mi][1] = (f32x4){t1, t1, t1, t1};
        }
    }
    gemm3(acc, sHi, sLo, w2hi, w2lo, w, l15, g);

    // ---- relu + column sum over rows 0..62 (row 63 is pad) ----
    float cs0 = 0.f, cs1 = 0.f;
    #pragma unroll
    for (int mi = 0; mi < 4; ++mi)
        #pragma unroll
        for (int r = 0; r < 4; ++r) {
            const bool pad = (mi == 3 && r == 3 && g == 3);   // row 63
            const float v0 = fmaxf(acc[mi][0][r], 0.f);
            const float v1 = fmaxf(acc[mi][1][r], 0.f);
            if (!pad) { cs0 += v0; cs1 += v1; }
        }
    cs0 += __shfl_xor(cs0, 16); cs0 += __shfl_xor(cs0, 32);
    cs1 += __shfl_xor(cs1, 16); cs1 += __shfl_xor(cs1, 32);
    if (g == 0) {
        out[(size_t)b * DIM + w * 32 + l15]      = cs0;
        out[(size_t)b * DIM + w * 32 + 16 + l15] = cs1;
    }
}

extern "C" void kernel_launch(void* const* d_in, const int* in_sizes, int n_in,
                              void* d_out, int out_size, void* d_ws, size_t ws_size,
                              hipStream_t stream) {
    const float* embs = (const float*)d_in[0];
    // d_in[1] = batch_idx (int64): deterministic -> unused
    const float* W1   = (const float*)d_in[2];
    const float* b1   = (const float*)d_in[3];
    const float* W2   = (const float*)d_in[4];
    const float* b2   = (const float*)d_in[5];
    float* out        = (float*)d_out;
    unsigned short* wt = (unsigned short*)d_ws;   // needs 128 KB

    const int nb = in_sizes[0] / (NODES * DIM);   // 4096

    pack_wt<<<256, 128, 0, stream>>>(W1, W2, wt);
    mlp_mfma<<<nb, 256, 0, stream>>>(embs, W1, b1, b2, wt, out);
}